// Round 1
// 642.177 us; speedup vs baseline: 2.3359x; 2.3359x over previous
//
#include <hip/hip_runtime.h>

typedef float vf4 __attribute__((ext_vector_type(4)));
typedef unsigned int uv4 __attribute__((ext_vector_type(4)));
typedef short bf16x8 __attribute__((ext_vector_type(8)));

constexpr int N_PTS = 1048576;
constexpr int D = 32;
constexpr int Q = 4;
constexpr int K = 256;
constexpr int BLOCK = 512;            // 8 waves; 64 points per wave (4 tiles of 16)
constexpr int NT = 4;                 // 16-point tiles per wave
constexpr int PTS_PER_BLOCK = 512;
constexpr int WS_STAGE_F = 16384;     // floats per stage block: [cbf 8192][fAhi 4096][fAlo 4096]
constexpr int WS_MC_OFF = Q * WS_STAGE_F;  // then Q*K floats of -0.5*||e||^2 (exact, seq-FMA order)
constexpr float TAU = 1e-3f;          // score-margin below which we replicate ref fp32 exactly

// round-to-nearest-even fp32 -> bf16 (returns 16-bit pattern in low bits)
__device__ __forceinline__ unsigned f2bf(float f) {
    unsigned u = __float_as_uint(f);
    return (u + 0x7FFFu + ((u >> 16) & 1u)) >> 16;
}

// ---------------------------------------------------------------------------
// Prologue: convert codebooks ONCE into d_ws:
//  - swizzled fp32 rows (k*32 + (dword ^ ((k&7)<<2))) for conflict-light LDS reads
//  - bf16 hi/lo A-operand fragments in lane-linear MFMA layout
//  - mc[q][k] = -0.5 * seqFMA(e*e)  (exact; rescue recovers c = -2*mc bitwise)
// ---------------------------------------------------------------------------
__global__ void rvq_prep(const float* __restrict__ cb, float* __restrict__ ws)
{
#pragma clang fp contract(off)
    const int t = blockIdx.x * 256 + threadIdx.x;   // 0..1023 = q*K + k
    const int q = t >> 8, k = t & (K - 1);
    float e[32];
    {
        const vf4* src = (const vf4*)(cb + (size_t)t * D);
        #pragma unroll
        for (int j = 0; j < 8; ++j) {
            vf4 v = src[j];
            e[4*j+0] = v.x; e[4*j+1] = v.y; e[4*j+2] = v.z; e[4*j+3] = v.w;
        }
    }
    float c = 0.0f;
    #pragma unroll
    for (int i = 0; i < 32; ++i) c = __builtin_fmaf(e[i], e[i], c);
    ws[WS_MC_OFF + q * K + k] = -0.5f * c;

    // swizzled fp32 rows
    float* cbf = ws + (size_t)q * WS_STAGE_F;
    const int sw = (k & 7) << 2;
    #pragma unroll
    for (int b = 0; b < 8; ++b) {
        vf4 v;
        v.x = e[4*b+0]; v.y = e[4*b+1]; v.z = e[4*b+2]; v.w = e[4*b+3];
        *(vf4*)(cbf + k * 32 + ((b * 4) ^ sw)) = v;
    }

    // bf16 hi/lo fragments, lane-linear: entry (ct*64 + g*16 + col) holds
    // code k=ct*16+col, dims [8g, 8g+8) as 8 bf16 (= one lane's A operand slice)
    uv4* fh = (uv4*)(ws + (size_t)q * WS_STAGE_F + 8192);
    uv4* fl = (uv4*)(ws + (size_t)q * WS_STAGE_F + 12288);
    const int ct = k >> 4, col = k & 15;
    #pragma unroll
    for (int g = 0; g < 4; ++g) {
        unsigned hu[4], lu[4];
        #pragma unroll
        for (int j2 = 0; j2 < 4; ++j2) {
            float f0 = e[8*g + 2*j2 + 0];
            float f1 = e[8*g + 2*j2 + 1];
            unsigned h0 = f2bf(f0), h1 = f2bf(f1);
            float l0 = f0 - __uint_as_float(h0 << 16);   // exact in fp32
            float l1 = f1 - __uint_as_float(h1 << 16);
            hu[j2] = h0 | (h1 << 16);
            lu[j2] = f2bf(l0) | (f2bf(l1) << 16);
        }
        uv4 H; H.x = hu[0]; H.y = hu[1]; H.z = hu[2]; H.w = hu[3];
        uv4 L; L.x = lu[0]; L.y = lu[1]; L.z = lu[2]; L.w = lu[3];
        fh[ct * 64 + g * 16 + col] = H;
        fl[ct * 64 + g * 16 + col] = L;
    }
}

// ---------------------------------------------------------------------------
// Main kernel: scores via 4-pass split-bf16 MFMA, exact-fp32 rescue on near-ties,
// bitwise-exact residual update chain.
// ---------------------------------------------------------------------------
__global__ __launch_bounds__(BLOCK, 4)
void rvq_kernel(const float* __restrict__ x, const float* __restrict__ ws,
                float* __restrict__ out_xq, float* __restrict__ out_loss,
                float* __restrict__ out_idx)
{
#pragma clang fp contract(off)
    extern __shared__ char lds[];                       // 65536 B
    float* lds_cbf = (float*)lds;                       // 8192 floats, swizzled rows
    const bf16x8* lds_fh = (const bf16x8*)(lds + 32768);
    const bf16x8* lds_fl = (const bf16x8*)(lds + 49152);

    const int tid  = threadIdx.x;
    const int w    = tid >> 6;
    const int lane = tid & 63;
    const int g    = lane >> 4;        // dim-chunk [8g, 8g+8)
    const int col  = lane & 15;        // point-within-tile / C column
    const long long blockbase = (long long)blockIdx.x * PTS_PER_BLOCK + w * 64;

    // residuals: lane holds dims [8g,8g+8) of point (blockbase + t*16 + col)
    float r[NT][8];
    #pragma unroll
    for (int t = 0; t < NT; ++t) {
        const vf4* xs = (const vf4*)(x + (size_t)(blockbase + t * 16 + col) * D + g * 8);
        vf4 a = xs[0], b = xs[1];
        r[t][0]=a.x; r[t][1]=a.y; r[t][2]=a.z; r[t][3]=a.w;
        r[t][4]=b.x; r[t][5]=b.y; r[t][6]=b.z; r[t][7]=b.w;
    }

    float loss_acc = 0.0f;
    unsigned idxp[NT] = {0u, 0u, 0u, 0u};

    for (int q = 0; q < Q; ++q) {
        __syncthreads();   // protect LDS from previous stage's readers
        {   // stage the 64KB prepared block: coalesced, conflict-free
            const uv4* s4 = (const uv4*)(ws + (size_t)q * WS_STAGE_F);
            uv4* d4 = (uv4*)lds;
            #pragma unroll
            for (int i = 0; i < 8; ++i) d4[i * BLOCK + tid] = s4[i * BLOCK + tid];
        }
        __syncthreads();

        // split residuals to bf16 hi/lo (RNE both levels; |delta| <= 2^-18 |r|)
        union U8 { bf16x8 v; unsigned u[4]; };
        U8 Bh[NT], Bl[NT];
        #pragma unroll
        for (int t = 0; t < NT; ++t) {
            #pragma unroll
            for (int j2 = 0; j2 < 4; ++j2) {
                float f0 = r[t][2*j2 + 0];
                float f1 = r[t][2*j2 + 1];
                unsigned h0 = f2bf(f0), h1 = f2bf(f1);
                float l0 = f0 - __uint_as_float(h0 << 16);
                float l1 = f1 - __uint_as_float(h1 << 16);
                Bh[t].u[j2] = h0 | (h1 << 16);
                Bl[t].u[j2] = f2bf(l0) | (f2bf(l1) << 16);
            }
        }

        float best[NT], best2[NT]; int bidx[NT];
        #pragma unroll
        for (int t = 0; t < NT; ++t) { best[t] = -1e30f; best2[t] = -1e30f; bidx[t] = 0; }

        const float* mcq = ws + WS_MC_OFF + q * K;

        // score = dot(r,e) - 0.5*||e||^2, maximized.  mc rides in as MFMA C-in.
        for (int ct = 0; ct < 16; ++ct) {
            bf16x8 Ah = lds_fh[ct * 64 + lane];
            bf16x8 Al = lds_fl[ct * 64 + lane];
            vf4 mc4 = *(const vf4*)(mcq + ct * 16 + g * 4);
            const int kbase = ct * 16 + g * 4;
            #pragma unroll
            for (int t = 0; t < NT; ++t) {
                vf4 acc = __builtin_amdgcn_mfma_f32_16x16x32_bf16(Ah, Bh[t].v, mc4, 0, 0, 0);
                acc = __builtin_amdgcn_mfma_f32_16x16x32_bf16(Ah, Bl[t].v, acc, 0, 0, 0);
                acc = __builtin_amdgcn_mfma_f32_16x16x32_bf16(Al, Bh[t].v, acc, 0, 0, 0);
                acc = __builtin_amdgcn_mfma_f32_16x16x32_bf16(Al, Bl[t].v, acc, 0, 0, 0);
                #pragma unroll
                for (int rr = 0; rr < 4; ++rr) {
                    float sc = acc[rr];
                    bool gt = sc > best[t];
                    best2[t] = gt ? best[t] : fmaxf(best2[t], sc);
                    best[t]  = gt ? sc : best[t];
                    bidx[t]  = gt ? (kbase + rr) : bidx[t];
                }
            }
        }

        // cross-lane argmax reduce (4 lanes per point), tiebreak = lower index
        #pragma unroll
        for (int t = 0; t < NT; ++t) {
            #pragma unroll
            for (int off = 16; off <= 32; off <<= 1) {
                float ob  = __shfl_xor(best[t], off, 64);
                float ob2 = __shfl_xor(best2[t], off, 64);
                int   oi  = __shfl_xor(bidx[t], off, 64);
                float nb2 = fmaxf(fminf(best[t], ob), fmaxf(best2[t], ob2));
                bool take = (ob > best[t]) || (ob == best[t] && oi < bidx[t]);
                best[t]  = take ? ob : best[t];
                bidx[t]  = take ? oi : bidx[t];
                best2[t] = nb2;
            }
        }

        // near-tie rescue: replicate sequential-fp32 (XLA-style) d exactly.
        // Wave-parallel: 4 codes/lane, first-min semantics via index tiebreak.
        #pragma unroll
        for (int t = 0; t < NT; ++t) {
            unsigned long long m = __ballot(best[t] - best2[t] < TAU) & 0xFFFFull;
            while (m) {
                const int p = __ffsll(m) - 1;
                m &= m - 1;
                float rr32[32];
                #pragma unroll
                for (int g2 = 0; g2 < 4; ++g2) {
                    #pragma unroll
                    for (int j = 0; j < 8; ++j)
                        rr32[g2*8 + j] = __shfl(r[t][j], p + 16 * g2, 64);
                }
                float A = 0.0f;
                #pragma unroll
                for (int i = 0; i < 32; ++i) A = __builtin_fmaf(rr32[i], rr32[i], A);
                float bd = 1e30f; int bi = K;
                for (int u = 0; u < 4; ++u) {
                    const int k = u * 64 + lane;
                    const float* row = lds_cbf + k * 32;
                    const int sw = (k & 7) << 2;
                    float acc = 0.0f;
                    #pragma unroll
                    for (int i = 0; i < 32; ++i)
                        acc = __builtin_fmaf(rr32[i], row[i ^ sw], acc);
                    float ck = -2.0f * mcq[k];          // bitwise c_k (seq-FMA order)
                    float dd = (A - 2.0f * acc) + ck;   // 2*acc exact; two roundings as ref
                    if (dd < bd) { bd = dd; bi = k; }   // ascending k: first-min
                }
                #pragma unroll
                for (int off = 1; off < 64; off <<= 1) {
                    float od = __shfl_xor(bd, off, 64);
                    int   oi = __shfl_xor(bi, off, 64);
                    if (od < bd || (od == bd && oi < bi)) { bd = od; bi = oi; }
                }
                if (col == p) bidx[t] = bi;
            }
        }

        // residual update, replicating the reference's 3-step fp32 chain:
        // t = fl(xq - r); xq_st = fl(r + t); r' = fl(r - xq_st)
        #pragma unroll
        for (int t = 0; t < NT; ++t) {
            const int k = bidx[t];
            const int sw = (k & 7) << 2;
            const float* rowp = lds_cbf + k * 32;
            vf4 e0 = *(const vf4*)(rowp + ((8 * g) ^ sw));
            vf4 e1 = *(const vf4*)(rowp + ((8 * g + 4) ^ sw));
            float ev[8] = {e0.x, e0.y, e0.z, e0.w, e1.x, e1.y, e1.z, e1.w};
            #pragma unroll
            for (int j = 0; j < 8; ++j) {
                float tt = ev[j] - r[t][j];
                float ss = r[t][j] + tt;
                r[t][j] = r[t][j] - ss;
                loss_acc = __builtin_fmaf(tt, tt, loss_acc);
            }
            idxp[t] |= ((unsigned)k) << (8 * q);   // byte q = stage q index
        }
    }

    // x_q = x - final residual (bitwise-equal selection path => matches ref closely)
    #pragma unroll
    for (int t = 0; t < NT; ++t) {
        const size_t po = (size_t)(blockbase + t * 16 + col) * D + g * 8;
        const vf4* xs = (const vf4*)(x + po);
        vf4 a = xs[0], b = xs[1];
        vf4 o0, o1;
        o0.x = a.x - r[t][0]; o0.y = a.y - r[t][1]; o0.z = a.z - r[t][2]; o0.w = a.w - r[t][3];
        o1.x = b.x - r[t][4]; o1.y = b.y - r[t][5]; o1.z = b.z - r[t][6]; o1.w = b.w - r[t][7];
        vf4* dst = (vf4*)(out_xq + po);
        dst[0] = o0; dst[1] = o1;
    }

    // indices: unpack bytes -> coalesced float4 per point (g==0 lanes own points)
    if (g == 0) {
        #pragma unroll
        for (int t = 0; t < NT; ++t) {
            vf4 iv;
            iv.x = (float)(idxp[t] & 255u);
            iv.y = (float)((idxp[t] >> 8) & 255u);
            iv.z = (float)((idxp[t] >> 16) & 255u);
            iv.w = (float)(idxp[t] >> 24);
            *(vf4*)(out_idx + (size_t)(blockbase + t * 16 + col) * Q) = iv;
        }
    }

    // loss: wave64 shuffle reduce, one atomic per wave
    #pragma unroll
    for (int off = 32; off > 0; off >>= 1)
        loss_acc += __shfl_down(loss_acc, off, 64);
    if (lane == 0) {
        const float scale = 1.25f / (float)((long long)Q * N_PTS * D);
        atomicAdd(out_loss, loss_acc * scale);
    }
}

extern "C" void kernel_launch(void* const* d_in, const int* in_sizes, int n_in,
                              void* d_out, int out_size, void* d_ws, size_t ws_size,
                              hipStream_t stream) {
    const float* x  = (const float*)d_in[0];
    const float* cb = (const float*)d_in[1];
    float* out      = (float*)d_out;
    float* out_xq   = out;                               // N*D
    float* out_loss = out + (size_t)N_PTS * D;           // 1
    float* out_idx  = out_loss + 1;                      // N*Q
    float* ws       = (float*)d_ws;                      // needs (Q*16384 + Q*256)*4 = 261 KB

    // harness poisons d_out with 0xAA before every timed launch
    hipMemsetAsync(out_loss, 0, sizeof(float), stream);

    rvq_prep<<<dim3(4), dim3(256), 0, stream>>>(cb, ws);
    rvq_kernel<<<dim3(N_PTS / PTS_PER_BLOCK), dim3(BLOCK), 65536, stream>>>(
        x, ws, out_xq, out_loss, out_idx);
}